// Round 3
// baseline (5909.029 us; speedup 1.0000x reference)
//
#include <hip/hip_runtime.h>

#define S_LEN 1024
#define BATCH 64
#define I_DIM 256
#define H_DIM 512
#define NCL 4      // clusters (16 batch rows each)
#define NRK 8      // WGs per cluster (64 feats each; 1 wave = 16 feats, full K)
#define ROWS 16
#define HSTR 520   // LDS row stride (bf16 elems) for h: 16B-aligned rows
#define XSTR 264   // LDS row stride (bf16) for x staging in precompute

typedef short short8 __attribute__((ext_vector_type(8)));
typedef float floatx4 __attribute__((ext_vector_type(4)));
typedef unsigned short ushortx4 __attribute__((ext_vector_type(4)));
typedef unsigned long long u64;

__device__ inline unsigned short f2bf(float x){
  unsigned u = __float_as_uint(x);
  u += 0x7fffu + ((u >> 16) & 1u);           // RNE
  return (unsigned short)(u >> 16);
}
__device__ inline float bf2f(unsigned short s){
  return __uint_as_float(((unsigned)s) << 16);
}
__device__ inline float fast_tanh(float x){
  float e = __expf(2.0f * x);                // inf-safe: +inf -> 1, 0 -> -1
  return 1.0f - 2.0f / (e + 1.0f);
}
__device__ inline float fast_sigmoid(float x){
  return 1.0f / (1.0f + __expf(-x));
}
__device__ inline short8 cvt8(const float* p){
  short8 r;
#pragma unroll
  for (int j = 0; j < 8; j++) r[j] = (short)f2bf(p[j]);
  return r;
}

// ---------------------------------------------------------------------------
// Kernel W: pre-convert W_in and tau_w1[:, :256] to bf16.
// ---------------------------------------------------------------------------
__global__ __launch_bounds__(256) void convert_weights_kernel(
  const float* __restrict__ W_in, const float* __restrict__ tau_w1,
  unsigned short* __restrict__ Wbf, unsigned short* __restrict__ Tbf)
{
  const int f = blockIdx.x, k = threadIdx.x;
  Wbf[f * I_DIM + k] = f2bf(W_in[(size_t)f * I_DIM + k]);
  Tbf[f * I_DIM + k] = f2bf(tau_w1[(size_t)f * (I_DIM + H_DIM) + k]);
}

// ---------------------------------------------------------------------------
// Kernel P: A_in[t][F][b], A_tau[t][F][b]  (bf16) — x staged once in LDS.
// ---------------------------------------------------------------------------
__global__ __launch_bounds__(256) void precompute_kernel(
  const float* __restrict__ x, const unsigned short* __restrict__ Wbf,
  const unsigned short* __restrict__ Tbf,
  const float* __restrict__ b_in, const float* __restrict__ tau_b1,
  unsigned short* __restrict__ A_in, unsigned short* __restrict__ A_tau)
{
  __shared__ unsigned short xs[BATCH * XSTR];
  const int t = blockIdx.x, tid = threadIdx.x;
  {
    const int br = tid >> 2, pp = tid & 3;
    const float* xrow = x + ((size_t)br * S_LEN + t) * I_DIM + pp * 64;
    unsigned short* drow = xs + br * XSTR + pp * 64;
#pragma unroll
    for (int c = 0; c < 16; c++){
      float4 v = *(const float4*)(xrow + c * 4);
      ushortx4 o; o[0] = f2bf(v.x); o[1] = f2bf(v.y); o[2] = f2bf(v.z); o[3] = f2bf(v.w);
      *(ushortx4*)(drow + c * 4) = o;
    }
  }
  __syncthreads();

  const int w = tid >> 6, l15 = tid & 15, q = (tid & 63) >> 4;
#pragma unroll 1
  for (int fb = 0; fb < 8; fb++){
    const int F = fb * 64 + w * 16 + l15;
    floatx4 accf[4], acct[4];
#pragma unroll
    for (int m = 0; m < 4; m++){ accf[m] = (floatx4){0,0,0,0}; acct[m] = (floatx4){0,0,0,0}; }
#pragma unroll
    for (int kc = 0; kc < 8; kc++){
      const int k0 = kc * 32 + q * 8;
      short8 bw = *(const short8*)&Wbf[F * I_DIM + k0];
      short8 bt = *(const short8*)&Tbf[F * I_DIM + k0];
#pragma unroll
      for (int m = 0; m < 4; m++){
        short8 a = *(const short8*)&xs[(m * 16 + l15) * XSTR + k0];
        accf[m] = __builtin_amdgcn_mfma_f32_16x16x32_bf16(a, bw, accf[m], 0, 0, 0);
        acct[m] = __builtin_amdgcn_mfma_f32_16x16x32_bf16(a, bt, acct[m], 0, 0, 0);
      }
    }
    const float bi = b_in[F], bt1 = tau_b1[F];
#pragma unroll
    for (int m = 0; m < 4; m++){
      ushortx4 pf, pt;
#pragma unroll
      for (int i2 = 0; i2 < 4; i2++){ pf[i2] = f2bf(accf[m][i2] + bi); pt[i2] = f2bf(acct[m][i2] + bt1); }
      const size_t base = ((size_t)t * H_DIM + F) * BATCH + m * 16 + q * 4;
      *(ushortx4*)(A_in + base) = pf;
      *(ushortx4*)(A_tau + base) = pt;
    }
  }
}

// ---------------------------------------------------------------------------
// Kernel S: persistent scan, 32 WGs x 256 thr (__launch_bounds__(256,1)).
//   cl = bid&3 (16 rows), rank = bid>>2 (64 feats; wave w owns 16 feats, K=512
//   in-register -> no cross-wave reduction). Sync = self-stamped data words:
//   f word = bf16|stamp<<16, tau word = f32|stamp<<32. No flags, no drain.
//   Parity-2 buffers; overwrite safety via value data-dependency chain.
// ---------------------------------------------------------------------------
__global__ __launch_bounds__(256, 1) void scan_kernel(
  const float* __restrict__ h0, const float* __restrict__ W_rec,
  const float* __restrict__ tau_w1, const float* __restrict__ tau_w2,
  const float* __restrict__ tau_b2_p, const float* __restrict__ gamma,
  const float* __restrict__ beta,
  const unsigned short* __restrict__ A_in, const unsigned short* __restrict__ A_tau,
  unsigned* __restrict__ bc_f, u64* __restrict__ bc_td,
  float* __restrict__ out0, float* __restrict__ outh, float* __restrict__ outtau)
{
  __shared__ unsigned short hB[ROWS * HSTR];   // 16.6 KB  h (bf16), padded rows

  const int tid = threadIdx.x;
  const int cl   = blockIdx.x & (NCL - 1);
  const int rank = blockIdx.x >> 2;            // 0..7
  const int w = tid >> 6, l15 = tid & 15, q = (tid & 63) >> 4;
  const int Fw = rank * 64 + w * 16 + l15;     // producer feat (B-frag n=l15)
  const int rr = tid >> 4;                     // consumer row 0..15
  const int cc = tid & 15;                     // consumer 32-feat chunk

  // ---- weight fragments, full K=512 for this wave's feat ----
  short8 wr[16], wt[16];
#pragma unroll
  for (int kc = 0; kc < 16; kc++){
    const int k = kc * 32 + q * 8;
    wr[kc] = cvt8(&W_rec[(size_t)Fw * H_DIM + k]);
    wt[kc] = cvt8(&tau_w1[(size_t)Fw * (I_DIM + H_DIM) + I_DIM + k]);
  }
  float h_reg[32], gamr[32], betr[32];
  {
    const int b = cl * ROWS + rr;
#pragma unroll
    for (int j = 0; j < 32; j++){
      float hv = h0[(size_t)b * H_DIM + cc * 32 + j];
      h_reg[j] = hv;
      hB[rr * HSTR + cc * 32 + j] = f2bf(hv);
      gamr[j] = gamma[cc * 32 + j];
      betr[j] = beta[cc * 32 + j];
    }
  }
  const float tw2v = tau_w2[Fw];
  const float tb2 = tau_b2_p[0];

  // prefetch A terms for t=0: 4 consecutive rows (q*4..q*4+3) for feat Fw
  ushortx4 afp, atp;
  {
    const size_t aidx = (size_t)Fw * BATCH + cl * ROWS + q * 4;
    afp = *(const ushortx4*)(A_in + aidx);
    atp = *(const ushortx4*)(A_tau + aidx);
  }
  __syncthreads();

  for (int t = 0; t < S_LEN; t++){
    const unsigned st = (unsigned)(t + 1);
    const int par = t & 1;
    const int pc16 = (par * NCL + cl) * ROWS;

    // ---- matvec: this wave's 16 feats, full K=512 from LDS h ----
    floatx4 Df = {0,0,0,0}, Dt = {0,0,0,0};
#pragma unroll
    for (int kc = 0; kc < 16; kc++){
      short8 ha = *(const short8*)&hB[l15 * HSTR + kc * 32 + q * 8];
      Df = __builtin_amdgcn_mfma_f32_16x16x32_bf16(ha, wr[kc], Df, 0, 0, 0);
      Dt = __builtin_amdgcn_mfma_f32_16x16x32_bf16(ha, wt[kc], Dt, 0, 0, 0);
    }
    // D layout: col=l15 -> feat Fw, row=q*4+i -> batch row
    float pd[4];
#pragma unroll
    for (int i = 0; i < 4; i++){
      float vf = fast_tanh(Df[i] + bf2f(afp[i]));
      float vt = fast_tanh(Dt[i] + bf2f(atp[i]));
      // stamped f word -> bc_f[(par,cl,row,feat)]
      __hip_atomic_store(&bc_f[(size_t)(pc16 + q * 4 + i) * H_DIM + Fw],
                         (unsigned)f2bf(vf) | (st << 16),
                         __ATOMIC_RELAXED, __HIP_MEMORY_SCOPE_AGENT);
      pd[i] = vt * tw2v;
    }
    // tau partial over this wave's 16 feats (xor<16 stays in q-group)
#pragma unroll
    for (int i = 0; i < 4; i++){
      pd[i] += __shfl_xor(pd[i], 1); pd[i] += __shfl_xor(pd[i], 2);
      pd[i] += __shfl_xor(pd[i], 4); pd[i] += __shfl_xor(pd[i], 8);
    }
    if (l15 == 0){
#pragma unroll
      for (int i = 0; i < 4; i++)
        __hip_atomic_store(&bc_td[(size_t)(pc16 + q * 4 + i) * 32 + rank * 4 + w],
                           (u64)__float_as_uint(pd[i]) | ((u64)st << 32),
                           __ATOMIC_RELAXED, __HIP_MEMORY_SCOPE_AGENT);
    }
    // prefetch A for t+1 (in flight during poll)
    if (t + 1 < S_LEN){
      const size_t aidx = ((size_t)(t + 1) * H_DIM + Fw) * BATCH + cl * ROWS + q * 4;
      afp = *(const ushortx4*)(A_in + aidx);
      atp = *(const ushortx4*)(A_tau + aidx);
    }
    __syncthreads();   // all waves done reading hB (consumers rewrite it below)

    // ---- stamped readback: full f row slice (rr, feats cc*32..+32) ----
    const u64* fsrc = (const u64*)&bc_f[(size_t)(pc16 + rr) * H_DIM + cc * 32];
    u64 tmp[16];
#pragma unroll
    for (int u = 0; u < 16; u++)
      tmp[u] = __hip_atomic_load(&fsrc[u], __ATOMIC_RELAXED, __HIP_MEMORY_SCOPE_AGENT);
    unsigned pend = 0;
#pragma unroll
    for (int u = 0; u < 16; u++){
      unsigned s0 = (unsigned)(tmp[u] >> 16) & 0xFFFFu;
      unsigned s1 = (unsigned)(tmp[u] >> 48);
      if (s0 != st || s1 != st) pend |= 1u << u;
    }
    while (pend){
#pragma unroll
      for (int u = 0; u < 16; u++) if (pend & (1u << u)){
        u64 v = __hip_atomic_load(&fsrc[u], __ATOMIC_RELAXED, __HIP_MEMORY_SCOPE_AGENT);
        unsigned s0 = (unsigned)(v >> 16) & 0xFFFFu;
        unsigned s1 = (unsigned)(v >> 48);
        if (s0 == st && s1 == st){ tmp[u] = v; pend &= ~(1u << u); }
      }
    }
    float fv[32];
#pragma unroll
    for (int u = 0; u < 16; u++){
      fv[2 * u]     = bf2f((unsigned short)(tmp[u] & 0xFFFFu));
      fv[2 * u + 1] = bf2f((unsigned short)((tmp[u] >> 32) & 0xFFFFu));
    }
    // ---- stamped tau readback: 2 partial words per thread ----
    const u64* tsrc = &bc_td[(size_t)(pc16 + rr) * 32];
    u64 t0, t1;
    do { t0 = __hip_atomic_load(&tsrc[cc], __ATOMIC_RELAXED, __HIP_MEMORY_SCOPE_AGENT); }
    while ((unsigned)(t0 >> 32) != st);
    do { t1 = __hip_atomic_load(&tsrc[cc + 16], __ATOMIC_RELAXED, __HIP_MEMORY_SCOPE_AGENT); }
    while ((unsigned)(t1 >> 32) != st);
    float td = __uint_as_float((unsigned)t0) + __uint_as_float((unsigned)t1);
    td += __shfl_xor(td, 1); td += __shfl_xor(td, 2);
    td += __shfl_xor(td, 4); td += __shfl_xor(td, 8);
    const float tau = 1.0f + 9.0f * fast_sigmoid(td + tb2);
    const float c2 = 0.1f / tau, c1 = 1.0f - c2;

    // ---- h_pre + LN ----
    float hp[32]; float s1 = 0.f, s2 = 0.f;
#pragma unroll
    for (int j = 0; j < 32; j++){
      float v2 = c1 * h_reg[j] + c2 * fv[j];
      hp[j] = v2; s1 += v2; s2 += v2 * v2;
    }
    s1 += __shfl_xor(s1, 1); s2 += __shfl_xor(s2, 1);
    s1 += __shfl_xor(s1, 2); s2 += __shfl_xor(s2, 2);
    s1 += __shfl_xor(s1, 4); s2 += __shfl_xor(s2, 4);
    s1 += __shfl_xor(s1, 8); s2 += __shfl_xor(s2, 8);
    const float mu = s1 * (1.0f / 512.0f);
    const float var = s2 * (1.0f / 512.0f) - mu * mu;
    const float rs = rsqrtf(var + 1e-5f);
#pragma unroll
    for (int j = 0; j < 32; j++) h_reg[j] = (hp[j] - mu) * rs * gamr[j] + betr[j];

    // h -> LDS bf16 for next matvec
#pragma unroll
    for (int u = 0; u < 4; u++){
      short8 hv;
#pragma unroll
      for (int e = 0; e < 8; e++) hv[e] = (short)f2bf(h_reg[u * 8 + e]);
      *(short8*)&hB[rr * HSTR + cc * 32 + u * 8] = hv;
    }
    // outputs: rank owns feats [rank*64, +64) = cc chunks {2*rank, 2*rank+1}
    if ((cc >> 1) == rank){
      float* dst = out0 + ((size_t)(cl * ROWS + rr) * S_LEN + t) * H_DIM + cc * 32;
#pragma unroll
      for (int u = 0; u < 8; u++) *(float4*)(dst + u * 4) = *(float4*)(h_reg + u * 4);
    }
    if (rank == 0 && cc == 0) outtau[(size_t)(cl * ROWS + rr) * S_LEN + t] = tau;
    if (t == S_LEN - 1 && rank == 0){
#pragma unroll
      for (int j = 0; j < 32; j++)
        outh[(size_t)(cl * ROWS + rr) * H_DIM + cc * 32 + j] = h_reg[j];
    }
    __syncthreads();
  }
}

extern "C" void kernel_launch(void* const* d_in, const int* in_sizes, int n_in,
                              void* d_out, int out_size, void* d_ws, size_t ws_size,
                              hipStream_t stream) {
  const float* x      = (const float*)d_in[0];
  const float* h0     = (const float*)d_in[1];
  const float* W_in   = (const float*)d_in[2];
  const float* b_in   = (const float*)d_in[3];
  const float* W_rec  = (const float*)d_in[4];
  const float* tau_w1 = (const float*)d_in[5];
  const float* tau_b1 = (const float*)d_in[6];
  const float* tau_w2 = (const float*)d_in[7];
  const float* tau_b2 = (const float*)d_in[8];
  const float* gamma  = (const float*)d_in[9];
  const float* beta   = (const float*)d_in[10];

  char* ws = (char*)d_ws;
  unsigned short* A_in  = (unsigned short*)(ws);                  // 67,108,864 B
  unsigned short* A_tau = (unsigned short*)(ws + 67108864);       // 67,108,864 B
  // precompute-phase scratch (Wbf/Tbf) and scan-phase broadcast buffers
  // OVERLAP (disjoint in time; stamps 1..1024 can't collide with bf16 weight
  // bit patterns, which would need sub-denormal magnitudes).
  char* scratch = ws + 134217728;
  unsigned short* Wbf  = (unsigned short*)(scratch);              // 262,144 B
  unsigned short* Tbf  = (unsigned short*)(scratch + 262144);     // 262,144 B
  unsigned*       bc_f = (unsigned*)(scratch);                    // 262,144 B
  u64*            bc_td= (u64*)(scratch + 262144);                //  32,768 B

  float* out0   = (float*)d_out;
  float* outh   = out0 + (size_t)BATCH * S_LEN * H_DIM;
  float* outtau = outh + (size_t)BATCH * H_DIM;

  convert_weights_kernel<<<dim3(H_DIM), 256, 0, stream>>>(W_in, tau_w1, Wbf, Tbf);
  precompute_kernel<<<dim3(S_LEN), 256, 0, stream>>>(x, Wbf, Tbf, b_in, tau_b1, A_in, A_tau);
  scan_kernel<<<dim3(NCL * NRK), 256, 0, stream>>>(h0, W_rec, tau_w1, tau_w2, tau_b2, gamma, beta,
                                                   A_in, A_tau, bc_f, bc_td,
                                                   out0, outh, outtau);
}